// Round 4
// baseline (915.141 us; speedup 1.0000x reference)
//
#include <hip/hip_runtime.h>

#define MM 4096
#define KK 4096
#define NN 11008
#define NP8 (NN/8)
#define KTILES (KK/32)
#define KSTEPS (KK/64)
#define LDA 40
#define LDB 34

#define W_BYTES ((size_t)NN * KK * 2)          // 90,177,536
#define X_BYTES ((size_t)MM * KK * 2)          // 33,554,432
#define WS_NEED (W_BYTES + X_BYTES)

typedef __bf16 bf16x8 __attribute__((ext_vector_type(8)));
typedef float f32x4 __attribute__((ext_vector_type(4)));

union U16 { uint4 u; bf16x8 v; };

__device__ __forceinline__ unsigned short b16(float a){
  union { __bf16 v; unsigned short u; } t;
  t.v = (__bf16)a;            // HW cvt, RNE
  return t.u;
}

// async global->LDS, 16B per lane; HW dest = wave-uniform base + lane*16
__device__ __forceinline__ void g2l16(const unsigned short* g, unsigned short* l){
  __builtin_amdgcn_global_load_lds(
      (const __attribute__((address_space(1))) unsigned int*)g,
      (__attribute__((address_space(3))) unsigned int*)l, 16, 0, 0);
}

// ---------------- pass 1a: x fp32 -> bf16 ----------------
__global__ __launch_bounds__(256) void cvt_x(const float* __restrict__ x,
                                             unsigned short* __restrict__ xb){
  size_t i = ((size_t)blockIdx.x * 256 + threadIdx.x) * 8;
  f32x4 a = *(const f32x4*)(x + i);
  f32x4 b = *(const f32x4*)(x + i + 4);
  union { unsigned short s[8]; uint4 u; } t;
  t.s[0]=b16(a[0]); t.s[1]=b16(a[1]); t.s[2]=b16(a[2]); t.s[3]=b16(a[3]);
  t.s[4]=b16(b[0]); t.s[5]=b16(b[1]); t.s[6]=b16(b[2]); t.s[7]=b16(b[3]);
  *(uint4*)(xb + i) = t.u;
}

// ---------------- pass 1b: AWQ dequant -> Wt[N][K] bf16 ----------------
__global__ __launch_bounds__(256) void dequant_w(
    const int* __restrict__ qweight, const int* __restrict__ qzeros,
    const float* __restrict__ scales, unsigned short* __restrict__ Wt){
  __shared__ unsigned int Ws32[128 * 17];
  const int t  = threadIdx.x;
  const int c0 = blockIdx.x * 16, n0 = blockIdx.x * 128;
  const int k0 = blockIdx.y * 128, g = blockIdx.y;
  const int bc = t & 15;
  const int kp = t >> 4;
  const int c  = c0 + bc;
  const int SH[8] = {0,16,4,20,8,24,12,28};

  float sreg[8], treg[8];
  {
    const float* sp = scales + (size_t)g*NN + 8*c;
    unsigned int qz = (unsigned int)qzeros[(size_t)g*NP8 + c];
    #pragma unroll
    for (int j=0;j<8;j++){
      float s = sp[j];
      float z = (float)((qz >> SH[j]) & 0xFu);
      sreg[j] = s;
      treg[j] = -(128.0f + z) * s;
    }
  }

  const int prow = t >> 1;
  const int phalf = t & 1;

  #pragma unroll 1
  for (int s = 0; s < 4; ++s){
    const int kk = s*32 + 2*kp;
    unsigned int q0 = (unsigned int)qweight[(size_t)(k0 + kk    )*NP8 + c];
    unsigned int q1 = (unsigned int)qweight[(size_t)(k0 + kk + 1)*NP8 + c];
    const unsigned int M4v = 0x000F000Fu, BBv = 0x43004300u;
    unsigned int ea[4], fa[4];
    ea[0]=(q0&M4v)|BBv; ea[1]=((q0>>4)&M4v)|BBv; ea[2]=((q0>>8)&M4v)|BBv; ea[3]=((q0>>12)&M4v)|BBv;
    fa[0]=(q1&M4v)|BBv; fa[1]=((q1>>4)&M4v)|BBv; fa[2]=((q1>>8)&M4v)|BBv; fa[3]=((q1>>12)&M4v)|BBv;
    #pragma unroll
    for (int j=0;j<8;j++){
      float e=(j&1)?__uint_as_float(ea[j>>1]&0xFFFF0000u):__uint_as_float(ea[j>>1]<<16);
      float f=(j&1)?__uint_as_float(fa[j>>1]&0xFFFF0000u):__uint_as_float(fa[j>>1]<<16);
      float w0 = fmaf(e, sreg[j], treg[j]);
      float w1 = fmaf(f, sreg[j], treg[j]);
      union { unsigned short h[2]; unsigned int u; } p;
      p.h[0]=b16(w0); p.h[1]=b16(w1);
      Ws32[(8*bc + j)*17 + kp] = p.u;
    }
    __syncthreads();
    {
      unsigned int v[8];
      #pragma unroll
      for (int cidx=0;cidx<8;cidx++) v[cidx] = Ws32[prow*17 + phalf*8 + cidx];
      uint4 u0 = make_uint4(v[0],v[1],v[2],v[3]);
      uint4 u1 = make_uint4(v[4],v[5],v[6],v[7]);
      unsigned short* dst = Wt + (size_t)(n0 + prow)*KK + k0 + s*32 + phalf*16;
      *(uint4*)(dst)     = u0;
      *(uint4*)(dst + 8) = u1;
    }
    __syncthreads();
  }
}

// ---------------- pass 2: 256x256 / BK=64 / 8-wave, race-free 8-phase ----------------
// One iteration = 2 K-tiles: T0=2i (buf0), T1=2i+1 (buf1). Per phase:
// {ds-read subtile for THIS phase's MFMA} [+ stages] -> barrier -> lgkmcnt(0)
// -> sched_barrier -> setprio(1) -> 16 MFMA -> setprio(0) -> barrier.
// STAGE PLACEMENT IS REGION-DEAD ONLY (round-2 lesson: same-phase stage+read
// of one region races cross-wave): A(b0) dead after P2 -> stage A(t2) at P3;
// B(b0) dead after P4 -> stage B(t2) at P5; A(b1) dead after P6 -> stage
// A(t3) at P7; B(b1) dead after P8 -> stage B(t1) at P1 (next odd tile).
// Counted waits: P4 vmcnt(4) completes tile 2i+1 (A staged prev P7, B at P1)
// before P5 reads buf1; P8 vmcnt(4) completes tile 2i+2 before next P1 reads
// buf0; final-iteration variants drain to 0.
__global__ __launch_bounds__(512, 2) void gemm256(
    const unsigned short* __restrict__ A,   // [M,K] bf16
    const unsigned short* __restrict__ B,   // [N,K] bf16
    const float* __restrict__ bias,
    float* __restrict__ out){
  extern __shared__ __align__(16) unsigned short smem[];  // 131072 B dynamic
  const int tid  = threadIdx.x;
  const int lane = tid & 63;
  const int wid  = tid >> 6;
  const int l16  = lane & 15;
  const int quad = lane >> 4;
  const int wm   = wid >> 2;        // 0..1  -> A rows wm*128..+127
  const int wn   = wid & 3;         // 0..3  -> B rows wn*64..+63
  const int m0   = blockIdx.x * 256;
  const int n0   = blockIdx.y * 256;

  // ds_read swizzle (verified: 0 bank conflicts): logical chunk c at row r
  // lives at physical chunk c ^ (r&7); (r&7)==(l16&7) for all frag rows.
  const int xv0  = (quad ^ (l16 & 7)) << 3;   // kh0 chunk offset (elems)
  const int xv1  = xv0 ^ 32;                  // kh1 (= chunk ^ 4)
  const int rowA = (wm*128 + l16) * 64;            // elem offset in A region
  const int rowB = 16384 + (wn*64 + l16) * 64;     // elem offset in B region
  unsigned short* const b0 = smem;                 // even K-tiles
  unsigned short* const b1 = smem + 32768;         // odd  K-tiles

  // stage addressing: linear LDS dest (tid*16B), inverse-swizzled global col
  const int srl   = tid >> 3;                              // 0..63
  const int scol  = ((tid & 7) ^ ((tid >> 3) & 7)) << 3;   // elem col, 8-aligned
  const unsigned short* gA = A + (size_t)(m0 + srl)*KK + scol;
  const unsigned short* gB = B + (size_t)(n0 + srl)*KK + scol;
  unsigned short* const lbase = smem + tid*8;

#define STAGE(mat, hf, tile) do { \
    const unsigned short* gsrc = ((mat) ? gB : gA) + (size_t)(hf)*128*KK + (size_t)(tile)*64; \
    unsigned short* ldst = lbase + (((tile)&1)*32768) + ((mat)*16384) + ((hf)*8192); \
    g2l16(gsrc, ldst); \
    g2l16(gsrc + (size_t)64*KK, ldst + 4096); \
  } while(0)

  bf16x8 afc[8][2], bfc[4][2];
  f32x4 acc[8][4];
  {
    float bv[4];
    #pragma unroll
    for (int ni=0;ni<4;ni++) bv[ni] = bias[n0 + wn*64 + ni*16 + l16];
    #pragma unroll
    for (int mi=0;mi<8;mi++)
      #pragma unroll
      for (int ni=0;ni<4;ni++)
        acc[mi][ni] = (f32x4){bv[ni], bv[ni], bv[ni], bv[ni]};
  }

#define RD_A(b, kh) do { \
    _Pragma("unroll") \
    for (int mi=0; mi<8; ++mi){ U16 u; \
      u.u = *(const uint4*)((b) + rowA + mi*1024 + ((kh)? xv1 : xv0)); \
      afc[mi][kh] = u.v; } \
  } while(0)

#define RD_B2(b, nb, kh) do { \
    _Pragma("unroll") \
    for (int nn=0; nn<2; ++nn){ U16 u; \
      u.u = *(const uint4*)((b) + rowB + ((nb)+nn)*1024 + ((kh)? xv1 : xv0)); \
      bfc[(nb)+nn][kh] = u.v; } \
  } while(0)

#define PHASE_SYNC() do { \
    __builtin_amdgcn_s_barrier(); \
    asm volatile("s_waitcnt lgkmcnt(0)" ::: "memory"); \
    __builtin_amdgcn_sched_barrier(0); \
    __builtin_amdgcn_s_setprio(1); \
  } while(0)

#define ENDPH() do { \
    __builtin_amdgcn_s_setprio(0); \
    __builtin_amdgcn_s_barrier(); \
  } while(0)

#define MFMA_Q(kh, nh) do { \
    _Pragma("unroll") \
    for (int mi=0; mi<8; ++mi){ \
      acc[mi][2*(nh)  ] = __builtin_amdgcn_mfma_f32_16x16x32_bf16(afc[mi][kh], bfc[2*(nh)  ][kh], acc[mi][2*(nh)  ], 0,0,0); \
      acc[mi][2*(nh)+1] = __builtin_amdgcn_mfma_f32_16x16x32_bf16(afc[mi][kh], bfc[2*(nh)+1][kh], acc[mi][2*(nh)+1], 0,0,0); } \
  } while(0)

  // prologue: tile0 all 4 half-tiles + tile1 {A-lo, A-hi}  (12 loads)
  STAGE(0,0,0); STAGE(0,1,0); STAGE(1,0,0); STAGE(1,1,0);
  STAGE(0,0,1); STAGE(0,1,1);
  asm volatile("s_waitcnt vmcnt(4)" ::: "memory");   // tile0's 8 loads landed
  __builtin_amdgcn_s_barrier();

  #pragma unroll 1
  for (int i = 0; i < 32; ++i){
    const int t1 = 2*i + 1;          // odd tile of this iter -> buf1
    const int t2 = 2*i + 2;          // next even tile -> buf0
    const int t3 = 2*i + 3;          // next odd tile  -> buf1
    const bool st2 = (t2 < KSTEPS);
    const bool st3 = (t3 < KSTEPS);

    // ===== K-tile T0 = 2i (buf0) =====
    // P1: af[kh0] + bf[0-1][kh0]; stage B(t1) [B(b1) dead since prev P8]
    RD_A(b0, 0); RD_B2(b0, 0, 0);
    STAGE(1, 0, t1); STAGE(1, 1, t1);
    PHASE_SYNC(); MFMA_Q(0, 0); ENDPH();
    // P2: af[kh1] + bf[2-3][kh0]; no stage  [A(b0) reads finish here]
    RD_A(b0, 1); RD_B2(b0, 2, 0);
    PHASE_SYNC(); MFMA_Q(0, 1); ENDPH();
    // P3: bf[0-1][kh1]; stage A(t2) [A(b0) dead after P2's barrier]
    RD_B2(b0, 0, 1);
    if (st2){ STAGE(0, 0, t2); STAGE(0, 1, t2); }
    PHASE_SYNC(); MFMA_Q(1, 0); ENDPH();
    // P4: bf[2-3][kh1]; counted wait -> tile t1 fully landed
    RD_B2(b0, 2, 1);
    if (st2) asm volatile("s_waitcnt vmcnt(4)" ::: "memory");
    else     asm volatile("s_waitcnt vmcnt(0)" ::: "memory");
    PHASE_SYNC(); MFMA_Q(1, 1); ENDPH();

    // ===== K-tile T1 = 2i+1 (buf1) =====
    // P5: af[kh0] + bf[0-1][kh0]; stage B(t2) [B(b0) dead after P4's barrier]
    RD_A(b1, 0); RD_B2(b1, 0, 0);
    if (st2){ STAGE(1, 0, t2); STAGE(1, 1, t2); }
    PHASE_SYNC(); MFMA_Q(0, 0); ENDPH();
    // P6: af[kh1] + bf[2-3][kh0]; no stage  [A(b1) reads finish here]
    RD_A(b1, 1); RD_B2(b1, 2, 0);
    PHASE_SYNC(); MFMA_Q(0, 1); ENDPH();
    // P7: bf[0-1][kh1]; stage A(t3) [A(b1) dead after P6's barrier]
    RD_B2(b1, 0, 1);
    if (st3){ STAGE(0, 0, t3); STAGE(0, 1, t3); }
    PHASE_SYNC(); MFMA_Q(1, 0); ENDPH();
    // P8: bf[2-3][kh1]; counted wait -> tile t2 fully landed
    RD_B2(b1, 2, 1);
    if (st3)      asm volatile("s_waitcnt vmcnt(4)" ::: "memory");
    else          asm volatile("s_waitcnt vmcnt(0)" ::: "memory");
    PHASE_SYNC(); MFMA_Q(1, 1); ENDPH();
  }
#undef STAGE
#undef RD_A
#undef RD_B2
#undef PHASE_SYNC
#undef ENDPH
#undef MFMA_Q

  #pragma unroll
  for (int mi=0;mi<8;mi++)
    #pragma unroll
    for (int ni=0;ni<4;ni++){
      const int n = n0 + wn*64 + ni*16 + l16;
      #pragma unroll
      for (int r=0;r<4;r++){
        const int m = m0 + wm*128 + mi*16 + quad*4 + r;
        out[(size_t)m*NN + n] = acc[mi][ni][r];
      }
    }
}

// ---------------- fallback: round-4 fused kernel (passing, 705 us) ----------------
__global__ __launch_bounds__(256, 3) void awq_gemm_fused(
    const float* __restrict__ x, const int* __restrict__ qweight,
    const int* __restrict__ qzeros, const float* __restrict__ scales,
    const float* __restrict__ bias, float* __restrict__ out){
  __shared__ __align__(16) unsigned short As[128*LDA];
  __shared__ __align__(16) unsigned short Bs[128*LDB];
  const int tid  = threadIdx.x;
  const int wid  = tid >> 6;
  const int lane = tid & 63;
  const int l16  = lane & 15;
  const int quad = lane >> 4;
  const int wm   = (wid >> 1) * 64;
  const int wn   = (wid & 1) * 64;
  const int m0   = blockIdx.y * 128;
  const int n0   = blockIdx.x * 128;
  const int c0   = blockIdx.x * 16;
  const int ar = tid >> 3, kq = tid & 7;
  const float* pax = x + (size_t)(m0 + ar)*KK + kq*4;
  const int bc  = tid & 15;
  const int br0 = (tid >> 4) * 2;
  const int* pb = qweight + (size_t)br0*NP8 + c0 + bc;
  const int SH[8] = {0,16,4,20,8,24,12,28};
  float sreg[8], treg[8];
  f32x4 acc[4][4];
  {
    float bv[4];
    #pragma unroll
    for (int ni=0;ni<4;ni++) bv[ni] = bias[n0 + wn + ni*16 + l16];
    #pragma unroll
    for (int mi=0;mi<4;mi++)
      #pragma unroll
      for (int ni=0;ni<4;ni++)
        acc[mi][ni] = (f32x4){bv[ni], bv[ni], bv[ni], bv[ni]};
  }
  #pragma unroll 1
  for (int kt = 0; kt < KTILES; ++kt) {
    f32x4 av[4];
    #pragma unroll
    for (int i=0;i<4;i++) av[i] = *(const f32x4*)(pax + (size_t)i*32*KK);
    unsigned int q0 = (unsigned int)pb[0];
    unsigned int q1 = (unsigned int)pb[NP8];
    pax += 32; pb += (size_t)32*NP8;
    if ((kt & 3) == 0) {
      const int g = kt >> 2;
      const float* sp = scales + (size_t)g*NN + n0 + 8*bc;
      unsigned int qz = (unsigned int)qzeros[(size_t)g*NP8 + c0 + bc];
      #pragma unroll
      for (int j=0;j<8;j++){
        float s = sp[j];
        float z = (float)((qz >> SH[j]) & 0xFu);
        sreg[j] = s; treg[j] = -(128.0f + z) * s;
      }
    }
    __syncthreads();
    #pragma unroll
    for (int i=0;i<4;i++){
      union { unsigned short s[4]; uint2 u; } t;
      t.s[0]=b16(av[i][0]); t.s[1]=b16(av[i][1]);
      t.s[2]=b16(av[i][2]); t.s[3]=b16(av[i][3]);
      *(uint2*)(&As[(i*32 + ar)*LDA + kq*4]) = t.u;
    }
    {
      const unsigned int M4v = 0x000F000Fu, BBv = 0x43004300u;
      unsigned int ea[4], fa[4];
      ea[0]=(q0&M4v)|BBv; ea[1]=((q0>>4)&M4v)|BBv; ea[2]=((q0>>8)&M4v)|BBv; ea[3]=((q0>>12)&M4v)|BBv;
      fa[0]=(q1&M4v)|BBv; fa[1]=((q1>>4)&M4v)|BBv; fa[2]=((q1>>8)&M4v)|BBv; fa[3]=((q1>>12)&M4v)|BBv;
      #pragma unroll
      for (int j=0;j<8;j++){
        float e=(j&1)?__uint_as_float(ea[j>>1]&0xFFFF0000u):__uint_as_float(ea[j>>1]<<16);
        float f=(j&1)?__uint_as_float(fa[j>>1]&0xFFFF0000u):__uint_as_float(fa[j>>1]<<16);
        union { unsigned short s[2]; unsigned int u; } t;
        t.s[0]=b16(fmaf(e,sreg[j],treg[j])); t.s[1]=b16(fmaf(f,sreg[j],treg[j]));
        *(unsigned int*)(&Bs[(8*bc + j)*LDB + br0]) = t.u;
      }
    }
    __syncthreads();
    bf16x8 af[4], bfr[4];
    #pragma unroll
    for (int mi=0;mi<4;mi++){
      union { uint4 u; bf16x8 v; } t;
      t.u = *(const uint4*)(&As[(wm + mi*16 + l16)*LDA + quad*8]);
      af[mi] = t.v;
    }
    #pragma unroll
    for (int ni=0;ni<4;ni++){
      const unsigned int* bp = (const unsigned int*)(&Bs[(wn + ni*16 + l16)*LDB + quad*8]);
      union { unsigned int u[4]; bf16x8 v; } t;
      t.u[0]=bp[0]; t.u[1]=bp[1]; t.u[2]=bp[2]; t.u[3]=bp[3];
      bfr[ni] = t.v;
    }
    #pragma unroll
    for (int mi=0;mi<4;mi++)
      #pragma unroll
      for (int ni=0;ni<4;ni++)
        acc[mi][ni] = __builtin_amdgcn_mfma_f32_16x16x32_bf16(af[mi], bfr[ni], acc[mi][ni], 0, 0, 0);
  }
  #pragma unroll
  for (int mi=0;mi<4;mi++)
    #pragma unroll
    for (int ni=0;ni<4;ni++){
      const int n = n0 + wn + ni*16 + l16;
      #pragma unroll
      for (int r=0;r<4;r++){
        const int m = m0 + wm + mi*16 + quad*4 + r;
        out[(size_t)m*NN + n] = acc[mi][ni][r];
      }
    }
}

extern "C" void kernel_launch(void* const* d_in, const int* in_sizes, int n_in,
                              void* d_out, int out_size, void* d_ws, size_t ws_size,
                              hipStream_t stream) {
  const float* x  = (const float*)d_in[0];
  const int* qw   = (const int*)d_in[1];
  const int* qz   = (const int*)d_in[2];
  const float* sc = (const float*)d_in[3];
  const float* bi = (const float*)d_in[4];
  float* out = (float*)d_out;

  if (ws_size >= WS_NEED) {
    static int s_attr_done = 0;
    if (!s_attr_done) {
      hipFuncSetAttribute(reinterpret_cast<const void*>(gemm256),
                          hipFuncAttributeMaxDynamicSharedMemorySize, 131072);
      s_attr_done = 1;
    }
    unsigned short* Wt = (unsigned short*)d_ws;                    // [N,K] bf16
    unsigned short* xb = (unsigned short*)((char*)d_ws + W_BYTES); // [M,K] bf16
    cvt_x<<<(MM*(size_t)KK)/8/256, 256, 0, stream>>>(x, xb);
    dequant_w<<<dim3(NP8/16, KK/128), 256, 0, stream>>>(qw, qz, sc, Wt);
    gemm256<<<dim3(MM/256, NN/256), 512, 131072, stream>>>(xb, Wt, bi, out);
  } else {
    awq_gemm_fused<<<dim3(NN/128, MM/128), 256, 0, stream>>>(x, qw, qz, sc, bi, out);
  }
}

// Round 5
// 666.538 us; speedup vs baseline: 1.3730x; 1.3730x over previous
//
#include <hip/hip_runtime.h>

#define MM 4096
#define KK 4096
#define NN 11008
#define NP8 (NN/8)
#define KTILES (KK/32)
#define KSTEPS (KK/64)
#define LDA 40
#define LDB 34
#define NDQ ((NP8/16)*(KK/128))   // 86*32 = 2752 dequant blocks
#define NCV ((MM*KK)/8/256)       // 8192 cvt blocks

#define W_BYTES ((size_t)NN * KK * 2)          // 90,177,536
#define X_BYTES ((size_t)MM * KK * 2)          // 33,554,432
#define WS_NEED (W_BYTES + X_BYTES)

typedef __bf16 bf16x8 __attribute__((ext_vector_type(8)));
typedef float f32x4 __attribute__((ext_vector_type(4)));

union U16 { uint4 u; bf16x8 v; };

__device__ __forceinline__ unsigned short b16(float a){
  union { __bf16 v; unsigned short u; } t;
  t.v = (__bf16)a;            // HW cvt, RNE
  return t.u;
}

// async global->LDS, 16B per lane; HW dest = wave-uniform base + lane*16
__device__ __forceinline__ void g2l16(const unsigned short* g, unsigned short* l){
  __builtin_amdgcn_global_load_lds(
      (const __attribute__((address_space(1))) unsigned int*)g,
      (__attribute__((address_space(3))) unsigned int*)l, 16, 0, 0);
}

// ---------------- pass 1 (fused): AWQ dequant -> Wt[N][K] bf16  AND  x f32->bf16 ----
// Blocks [0, NDQ): dequant (body identical to the round-1 dequant_w kernel).
// Blocks [NDQ, NDQ+NCV): x conversion (body identical to round-1 cvt_x).
// Fusing overlaps the two memory streams and removes one launch gap.
__global__ __launch_bounds__(256) void prep_fused(
    const float* __restrict__ x, const int* __restrict__ qweight,
    const int* __restrict__ qzeros, const float* __restrict__ scales,
    unsigned short* __restrict__ Wt, unsigned short* __restrict__ xb){
  __shared__ unsigned int Ws32[128 * 17];
  const int bid = blockIdx.x;
  const int t   = threadIdx.x;

  if (bid >= NDQ){
    // ---- cvt branch ----
    size_t i = ((size_t)(bid - NDQ) * 256 + t) * 8;
    f32x4 a = *(const f32x4*)(x + i);
    f32x4 b = *(const f32x4*)(x + i + 4);
    union { unsigned short s[8]; uint4 u; } tt;
    tt.s[0]=b16(a[0]); tt.s[1]=b16(a[1]); tt.s[2]=b16(a[2]); tt.s[3]=b16(a[3]);
    tt.s[4]=b16(b[0]); tt.s[5]=b16(b[1]); tt.s[6]=b16(b[2]); tt.s[7]=b16(b[3]);
    *(uint4*)(xb + i) = tt.u;
    return;
  }

  // ---- dequant branch ----
  const int cx = bid % (NP8/16);        // 0..85
  const int ky = bid / (NP8/16);        // 0..31
  const int c0 = cx * 16, n0 = cx * 128;
  const int k0 = ky * 128, g = ky;      // group == 128 k-rows
  const int bc = t & 15;                // packed col (coalesced)
  const int kp = t >> 4;                // 0..15 k-pairs within slab
  const int c  = c0 + bc;
  const int SH[8] = {0,16,4,20,8,24,12,28};

  float sreg[8], treg[8];
  {
    const float* sp = scales + (size_t)g*NN + 8*c;
    unsigned int qz = (unsigned int)qzeros[(size_t)g*NP8 + c];
    #pragma unroll
    for (int j=0;j<8;j++){
      float s = sp[j];
      float z = (float)((qz >> SH[j]) & 0xFu);
      sreg[j] = s;
      treg[j] = -(128.0f + z) * s;
    }
  }

  const int prow = t >> 1;
  const int phalf = t & 1;

  #pragma unroll 1
  for (int s = 0; s < 4; ++s){
    const int kk = s*32 + 2*kp;
    unsigned int q0 = (unsigned int)qweight[(size_t)(k0 + kk    )*NP8 + c];
    unsigned int q1 = (unsigned int)qweight[(size_t)(k0 + kk + 1)*NP8 + c];
    const unsigned int M4v = 0x000F000Fu, BBv = 0x43004300u;
    unsigned int ea[4], fa[4];
    ea[0]=(q0&M4v)|BBv; ea[1]=((q0>>4)&M4v)|BBv; ea[2]=((q0>>8)&M4v)|BBv; ea[3]=((q0>>12)&M4v)|BBv;
    fa[0]=(q1&M4v)|BBv; fa[1]=((q1>>4)&M4v)|BBv; fa[2]=((q1>>8)&M4v)|BBv; fa[3]=((q1>>12)&M4v)|BBv;
    #pragma unroll
    for (int j=0;j<8;j++){
      float e=(j&1)?__uint_as_float(ea[j>>1]&0xFFFF0000u):__uint_as_float(ea[j>>1]<<16);
      float f=(j&1)?__uint_as_float(fa[j>>1]&0xFFFF0000u):__uint_as_float(fa[j>>1]<<16);
      float w0 = fmaf(e, sreg[j], treg[j]);    // k even
      float w1 = fmaf(f, sreg[j], treg[j]);    // k odd
      union { unsigned short h[2]; unsigned int u; } p;
      p.h[0]=b16(w0); p.h[1]=b16(w1);
      Ws32[(8*bc + j)*17 + kp] = p.u;
    }
    __syncthreads();
    {
      unsigned int v[8];
      #pragma unroll
      for (int cidx=0;cidx<8;cidx++) v[cidx] = Ws32[prow*17 + phalf*8 + cidx];
      uint4 u0 = make_uint4(v[0],v[1],v[2],v[3]);
      uint4 u1 = make_uint4(v[4],v[5],v[6],v[7]);
      unsigned short* dst = Wt + (size_t)(n0 + prow)*KK + k0 + s*32 + phalf*16;
      *(uint4*)(dst)     = u0;
      *(uint4*)(dst + 8) = u1;
    }
    __syncthreads();
  }
}

// ---------------- pass 2: 256x256 / BK=64 / 8-wave phase-split GEMM ----------------
// MEASURED-BEST schedule (round-1 bench: 413 us, MfmaUtil 38.7, 0 bank conflicts).
// Race-free by construction: buf(t&1)'s last ds_reads complete into registers at
// P2's lgkmcnt(0) before P2's end-barrier; tile t+2's stages (same buffer) issue
// only after that barrier. vmcnt(8) keeps tile t+1's 8 loads in flight; one
// counted wait per K-step.
__global__ __launch_bounds__(512, 2) void gemm256(
    const unsigned short* __restrict__ A,   // [M,K] bf16
    const unsigned short* __restrict__ B,   // [N,K] bf16
    const float* __restrict__ bias,
    float* __restrict__ out){
  extern __shared__ __align__(16) unsigned short smem[];  // 131072 B dynamic
  const int tid  = threadIdx.x;
  const int lane = tid & 63;
  const int wid  = tid >> 6;
  const int l16  = lane & 15;
  const int quad = lane >> 4;
  const int wm   = wid >> 2;        // 0..1  -> A rows wm*128..+127
  const int wn   = wid & 3;         // 0..3  -> B rows wn*64..+63
  const int m0   = blockIdx.x * 256;
  const int n0   = blockIdx.y * 256;

  // ds_read swizzle: chunk xor value is mi/ni-independent (rows step by 16)
  const int xv0  = (quad ^ (l16 & 7)) << 3;   // khalf0 chunk offset (elems)
  const int xv1  = xv0 ^ 32;                  // khalf1 (= ^ (4<<3))
  const int rowA = (wm*128 + l16) * 64;            // elem offset in A region
  const int rowB = 16384 + (wn*64 + l16) * 64;     // elem offset, B region

  // stage addressing: thread t covers linear LDS bytes t*16 (+8KB for call 1);
  // inverse-swizzled global source row/col:
  const int srl   = tid >> 3;                              // 0..63
  const int scol  = ((tid & 7) ^ ((tid >> 3) & 7)) << 3;   // elem col, 8-aligned
  const int sloff = tid * 8;                               // ushort off in 8KB

#define STAGE(mat, hf, s) do { \
    const unsigned short* gsrc = ((mat) ? B + (size_t)(n0 + (hf)*128 + srl)*KK \
                                        : A + (size_t)(m0 + (hf)*128 + srl)*KK) \
                                 + (size_t)(s)*64 + scol; \
    unsigned short* ldst = smem + (((s)&1)<<15) + ((mat)<<14) + ((hf)<<13) + sloff; \
    g2l16(gsrc, ldst); \
    g2l16(gsrc + (size_t)64*KK, ldst + 4096); \
  } while(0)

  f32x4 acc[8][4];
  {
    float bv[4];
    #pragma unroll
    for (int ni=0;ni<4;ni++) bv[ni] = bias[n0 + wn*64 + ni*16 + l16];
    #pragma unroll
    for (int mi=0;mi<8;mi++)
      #pragma unroll
      for (int ni=0;ni<4;ni++)
        acc[mi][ni] = (f32x4){bv[ni], bv[ni], bv[ni], bv[ni]};
  }

  // prologue: K0 fully + K1 fully in flight; wait for K0 only (vmcnt(8))
  STAGE(0,0,0); STAGE(0,1,0); STAGE(1,0,0); STAGE(1,1,0);
  STAGE(0,0,1); STAGE(0,1,1); STAGE(1,0,1); STAGE(1,1,1);
  asm volatile("s_waitcnt vmcnt(8)" ::: "memory");
  __builtin_amdgcn_s_barrier();

  #pragma unroll 1
  for (int t = 0; t < KSTEPS; ++t){
    const unsigned short* Ab = smem + ((t&1)<<15);
    bf16x8 af0[8], af1[8], bf0[4], bf1[4];

    // ---- phase 1: read khalf0 frags; MFMA kh0 x ni{0,1}
    #pragma unroll
    for (int mi=0;mi<8;mi++){ U16 u; u.u = *(const uint4*)(Ab + rowA + mi*1024 + xv0); af0[mi]=u.v; }
    #pragma unroll
    for (int ni=0;ni<4;ni++){ U16 u; u.u = *(const uint4*)(Ab + rowB + ni*1024 + xv0); bf0[ni]=u.v; }
    __builtin_amdgcn_s_barrier();
    __builtin_amdgcn_s_setprio(1);
    #pragma unroll
    for (int mi=0;mi<8;mi++){
      acc[mi][0] = __builtin_amdgcn_mfma_f32_16x16x32_bf16(af0[mi], bf0[0], acc[mi][0], 0,0,0);
      acc[mi][1] = __builtin_amdgcn_mfma_f32_16x16x32_bf16(af0[mi], bf0[1], acc[mi][1], 0,0,0);
    }
    __builtin_amdgcn_s_setprio(0);
    __builtin_amdgcn_s_barrier();

    // ---- phase 2: read khalf1 frags; MFMA kh0 x ni{2,3}
    #pragma unroll
    for (int mi=0;mi<8;mi++){ U16 u; u.u = *(const uint4*)(Ab + rowA + mi*1024 + xv1); af1[mi]=u.v; }
    #pragma unroll
    for (int ni=0;ni<4;ni++){ U16 u; u.u = *(const uint4*)(Ab + rowB + ni*1024 + xv1); bf1[ni]=u.v; }
    __builtin_amdgcn_s_barrier();
    __builtin_amdgcn_s_setprio(1);
    #pragma unroll
    for (int mi=0;mi<8;mi++){
      acc[mi][2] = __builtin_amdgcn_mfma_f32_16x16x32_bf16(af0[mi], bf0[2], acc[mi][2], 0,0,0);
      acc[mi][3] = __builtin_amdgcn_mfma_f32_16x16x32_bf16(af0[mi], bf0[3], acc[mi][3], 0,0,0);
    }
    __builtin_amdgcn_s_setprio(0);
    __builtin_amdgcn_s_barrier();
    // all reads of buf(t&1) are now complete in every wave -> safe to restage it

    // ---- phase 3: stage K+2 (A-lo, B-lo) into buf(t&1); MFMA kh1 x ni{0,1}
    if (t + 2 < KSTEPS){ STAGE(0,0,t+2); STAGE(1,0,t+2); }
    __builtin_amdgcn_s_barrier();
    __builtin_amdgcn_s_setprio(1);
    #pragma unroll
    for (int mi=0;mi<8;mi++){
      acc[mi][0] = __builtin_amdgcn_mfma_f32_16x16x32_bf16(af1[mi], bf1[0], acc[mi][0], 0,0,0);
      acc[mi][1] = __builtin_amdgcn_mfma_f32_16x16x32_bf16(af1[mi], bf1[1], acc[mi][1], 0,0,0);
    }
    __builtin_amdgcn_s_setprio(0);
    __builtin_amdgcn_s_barrier();

    // ---- phase 4: stage K+2 (A-hi, B-hi); MFMA kh1 x ni{2,3}; counted wait
    if (t + 2 < KSTEPS){ STAGE(0,1,t+2); STAGE(1,1,t+2); }
    __builtin_amdgcn_s_barrier();
    __builtin_amdgcn_s_setprio(1);
    #pragma unroll
    for (int mi=0;mi<8;mi++){
      acc[mi][2] = __builtin_amdgcn_mfma_f32_16x16x32_bf16(af1[mi], bf1[2], acc[mi][2], 0,0,0);
      acc[mi][3] = __builtin_amdgcn_mfma_f32_16x16x32_bf16(af1[mi], bf1[3], acc[mi][3], 0,0,0);
    }
    __builtin_amdgcn_s_setprio(0);
    // K+1 must be landed before next iteration's reads; K+2's 8 loads may fly.
    if (t < KSTEPS - 2) asm volatile("s_waitcnt vmcnt(8)" ::: "memory");
    else                asm volatile("s_waitcnt vmcnt(0)" ::: "memory");
    __builtin_amdgcn_s_barrier();
  }
#undef STAGE

  #pragma unroll
  for (int mi=0;mi<8;mi++)
    #pragma unroll
    for (int ni=0;ni<4;ni++){
      const int n = n0 + wn*64 + ni*16 + l16;
      #pragma unroll
      for (int r=0;r<4;r++){
        const int m = m0 + wm*128 + mi*16 + quad*4 + r;
        out[(size_t)m*NN + n] = acc[mi][ni][r];
      }
    }
}

// ---------------- fallback: round-4 fused kernel (passing, 705 us) ----------------
__global__ __launch_bounds__(256, 3) void awq_gemm_fused(
    const float* __restrict__ x, const int* __restrict__ qweight,
    const int* __restrict__ qzeros, const float* __restrict__ scales,
    const float* __restrict__ bias, float* __restrict__ out){
  __shared__ __align__(16) unsigned short As[128*LDA];
  __shared__ __align__(16) unsigned short Bs[128*LDB];
  const int tid  = threadIdx.x;
  const int wid  = tid >> 6;
  const int lane = tid & 63;
  const int l16  = lane & 15;
  const int quad = lane >> 4;
  const int wm   = (wid >> 1) * 64;
  const int wn   = (wid & 1) * 64;
  const int m0   = blockIdx.y * 128;
  const int n0   = blockIdx.x * 128;
  const int c0   = blockIdx.x * 16;
  const int ar = tid >> 3, kq = tid & 7;
  const float* pax = x + (size_t)(m0 + ar)*KK + kq*4;
  const int bc  = tid & 15;
  const int br0 = (tid >> 4) * 2;
  const int* pb = qweight + (size_t)br0*NP8 + c0 + bc;
  const int SH[8] = {0,16,4,20,8,24,12,28};
  float sreg[8], treg[8];
  f32x4 acc[4][4];
  {
    float bv[4];
    #pragma unroll
    for (int ni=0;ni<4;ni++) bv[ni] = bias[n0 + wn + ni*16 + l16];
    #pragma unroll
    for (int mi=0;mi<4;mi++)
      #pragma unroll
      for (int ni=0;ni<4;ni++)
        acc[mi][ni] = (f32x4){bv[ni], bv[ni], bv[ni], bv[ni]};
  }
  #pragma unroll 1
  for (int kt = 0; kt < KTILES; ++kt) {
    f32x4 av[4];
    #pragma unroll
    for (int i=0;i<4;i++) av[i] = *(const f32x4*)(pax + (size_t)i*32*KK);
    unsigned int q0 = (unsigned int)pb[0];
    unsigned int q1 = (unsigned int)pb[NP8];
    pax += 32; pb += (size_t)32*NP8;
    if ((kt & 3) == 0) {
      const int g = kt >> 2;
      const float* sp = scales + (size_t)g*NN + n0 + 8*bc;
      unsigned int qz = (unsigned int)qzeros[(size_t)g*NP8 + c0 + bc];
      #pragma unroll
      for (int j=0;j<8;j++){
        float s = sp[j];
        float z = (float)((qz >> SH[j]) & 0xFu);
        sreg[j] = s; treg[j] = -(128.0f + z) * s;
      }
    }
    __syncthreads();
    #pragma unroll
    for (int i=0;i<4;i++){
      union { unsigned short s[4]; uint2 u; } t;
      t.s[0]=b16(av[i][0]); t.s[1]=b16(av[i][1]);
      t.s[2]=b16(av[i][2]); t.s[3]=b16(av[i][3]);
      *(uint2*)(&As[(i*32 + ar)*LDA + kq*4]) = t.u;
    }
    {
      const unsigned int M4v = 0x000F000Fu, BBv = 0x43004300u;
      unsigned int ea[4], fa[4];
      ea[0]=(q0&M4v)|BBv; ea[1]=((q0>>4)&M4v)|BBv; ea[2]=((q0>>8)&M4v)|BBv; ea[3]=((q0>>12)&M4v)|BBv;
      fa[0]=(q1&M4v)|BBv; fa[1]=((q1>>4)&M4v)|BBv; fa[2]=((q1>>8)&M4v)|BBv; fa[3]=((q1>>12)&M4v)|BBv;
      #pragma unroll
      for (int j=0;j<8;j++){
        float e=(j&1)?__uint_as_float(ea[j>>1]&0xFFFF0000u):__uint_as_float(ea[j>>1]<<16);
        float f=(j&1)?__uint_as_float(fa[j>>1]&0xFFFF0000u):__uint_as_float(fa[j>>1]<<16);
        union { unsigned short s[2]; unsigned int u; } t;
        t.s[0]=b16(fmaf(e,sreg[j],treg[j])); t.s[1]=b16(fmaf(f,sreg[j],treg[j]));
        *(unsigned int*)(&Bs[(8*bc + j)*LDB + br0]) = t.u;
      }
    }
    __syncthreads();
    bf16x8 af[4], bfr[4];
    #pragma unroll
    for (int mi=0;mi<4;mi++){
      union { uint4 u; bf16x8 v; } t;
      t.u = *(const uint4*)(&As[(wm + mi*16 + l16)*LDA + quad*8]);
      af[mi] = t.v;
    }
    #pragma unroll
    for (int ni=0;ni<4;ni++){
      const unsigned int* bp = (const unsigned int*)(&Bs[(wn + ni*16 + l16)*LDB + quad*8]);
      union { unsigned int u[4]; bf16x8 v; } t;
      t.u[0]=bp[0]; t.u[1]=bp[1]; t.u[2]=bp[2]; t.u[3]=bp[3];
      bfr[ni] = t.v;
    }
    #pragma unroll
    for (int mi=0;mi<4;mi++)
      #pragma unroll
      for (int ni=0;ni<4;ni++)
        acc[mi][ni] = __builtin_amdgcn_mfma_f32_16x16x32_bf16(af[mi], bfr[ni], acc[mi][ni], 0, 0, 0);
  }
  #pragma unroll
  for (int mi=0;mi<4;mi++)
    #pragma unroll
    for (int ni=0;ni<4;ni++){
      const int n = n0 + wn + ni*16 + l16;
      #pragma unroll
      for (int r=0;r<4;r++){
        const int m = m0 + wm + mi*16 + quad*4 + r;
        out[(size_t)m*NN + n] = acc[mi][ni][r];
      }
    }
}

extern "C" void kernel_launch(void* const* d_in, const int* in_sizes, int n_in,
                              void* d_out, int out_size, void* d_ws, size_t ws_size,
                              hipStream_t stream) {
  const float* x  = (const float*)d_in[0];
  const int* qw   = (const int*)d_in[1];
  const int* qz   = (const int*)d_in[2];
  const float* sc = (const float*)d_in[3];
  const float* bi = (const float*)d_in[4];
  float* out = (float*)d_out;

  if (ws_size >= WS_NEED) {
    static int s_attr_done = 0;
    if (!s_attr_done) {
      hipFuncSetAttribute(reinterpret_cast<const void*>(gemm256),
                          hipFuncAttributeMaxDynamicSharedMemorySize, 131072);
      s_attr_done = 1;
    }
    unsigned short* Wt = (unsigned short*)d_ws;                    // [N,K] bf16
    unsigned short* xb = (unsigned short*)((char*)d_ws + W_BYTES); // [M,K] bf16
    prep_fused<<<NDQ + NCV, 256, 0, stream>>>(x, qw, qz, sc, Wt, xb);
    gemm256<<<dim3(MM/256, NN/256), 512, 131072, stream>>>(xb, Wt, bi, out);
  } else {
    awq_gemm_fused<<<dim3(NN/128, MM/128), 256, 0, stream>>>(x, qw, qz, sc, bi, out);
  }
}

// Round 6
// 627.772 us; speedup vs baseline: 1.4578x; 1.0618x over previous
//
#include <hip/hip_runtime.h>

#define MM 4096
#define KK 4096
#define NN 11008
#define NP8 (NN/8)
#define KTILES (KK/32)
#define KSTEPS (KK/64)
#define LDA 40
#define LDB 34
#define NDQ ((NP8/16)*(KK/128))   // 86*32 = 2752 dequant blocks
#define NCV ((MM*KK)/8/256)       // 8192 cvt blocks

#define W_BYTES ((size_t)NN * KK * 2)          // 90,177,536
#define X_BYTES ((size_t)MM * KK * 2)          // 33,554,432
#define WS_NEED (W_BYTES + X_BYTES)

typedef __bf16 bf16x8 __attribute__((ext_vector_type(8)));
typedef float f32x4 __attribute__((ext_vector_type(4)));

union U16 { uint4 u; bf16x8 v; };

__device__ __forceinline__ unsigned short b16(float a){
  union { __bf16 v; unsigned short u; } t;
  t.v = (__bf16)a;            // HW cvt, RNE
  return t.u;
}

// async global->LDS, 16B per lane; HW dest = wave-uniform base + lane*16
__device__ __forceinline__ void g2l16(const unsigned short* g, unsigned short* l){
  __builtin_amdgcn_global_load_lds(
      (const __attribute__((address_space(1))) unsigned int*)g,
      (__attribute__((address_space(3))) unsigned int*)l, 16, 0, 0);
}

// ---------------- pass 1 (fused): AWQ dequant -> Wt[N][K] bf16  AND  x f32->bf16 ----
__global__ __launch_bounds__(256) void prep_fused(
    const float* __restrict__ x, const int* __restrict__ qweight,
    const int* __restrict__ qzeros, const float* __restrict__ scales,
    unsigned short* __restrict__ Wt, unsigned short* __restrict__ xb){
  __shared__ unsigned int Ws32[128 * 17];
  const int bid = blockIdx.x;
  const int t   = threadIdx.x;

  if (bid >= NDQ){
    // ---- cvt branch ----
    size_t i = ((size_t)(bid - NDQ) * 256 + t) * 8;
    f32x4 a = *(const f32x4*)(x + i);
    f32x4 b = *(const f32x4*)(x + i + 4);
    union { unsigned short s[8]; uint4 u; } tt;
    tt.s[0]=b16(a[0]); tt.s[1]=b16(a[1]); tt.s[2]=b16(a[2]); tt.s[3]=b16(a[3]);
    tt.s[4]=b16(b[0]); tt.s[5]=b16(b[1]); tt.s[6]=b16(b[2]); tt.s[7]=b16(b[3]);
    *(uint4*)(xb + i) = tt.u;
    return;
  }

  // ---- dequant branch ----
  const int cx = bid % (NP8/16);        // 0..85
  const int ky = bid / (NP8/16);        // 0..31
  const int c0 = cx * 16, n0 = cx * 128;
  const int k0 = ky * 128, g = ky;      // group == 128 k-rows
  const int bc = t & 15;                // packed col (coalesced)
  const int kp = t >> 4;                // 0..15 k-pairs within slab
  const int c  = c0 + bc;
  const int SH[8] = {0,16,4,20,8,24,12,28};

  float sreg[8], treg[8];
  {
    const float* sp = scales + (size_t)g*NN + 8*c;
    unsigned int qz = (unsigned int)qzeros[(size_t)g*NP8 + c];
    #pragma unroll
    for (int j=0;j<8;j++){
      float s = sp[j];
      float z = (float)((qz >> SH[j]) & 0xFu);
      sreg[j] = s;
      treg[j] = -(128.0f + z) * s;
    }
  }

  // hoist all 8 qweight loads (independent; removes per-slab latency serialization)
  unsigned int q[4][2];
  #pragma unroll
  for (int s = 0; s < 4; ++s){
    const int kk = s*32 + 2*kp;
    q[s][0] = (unsigned int)qweight[(size_t)(k0 + kk    )*NP8 + c];
    q[s][1] = (unsigned int)qweight[(size_t)(k0 + kk + 1)*NP8 + c];
  }

  const int prow = t >> 1;
  const int phalf = t & 1;

  #pragma unroll
  for (int s = 0; s < 4; ++s){
    const unsigned int q0 = q[s][0], q1 = q[s][1];
    const unsigned int M4v = 0x000F000Fu, BBv = 0x43004300u;
    unsigned int ea[4], fa[4];
    ea[0]=(q0&M4v)|BBv; ea[1]=((q0>>4)&M4v)|BBv; ea[2]=((q0>>8)&M4v)|BBv; ea[3]=((q0>>12)&M4v)|BBv;
    fa[0]=(q1&M4v)|BBv; fa[1]=((q1>>4)&M4v)|BBv; fa[2]=((q1>>8)&M4v)|BBv; fa[3]=((q1>>12)&M4v)|BBv;
    #pragma unroll
    for (int j=0;j<8;j++){
      float e=(j&1)?__uint_as_float(ea[j>>1]&0xFFFF0000u):__uint_as_float(ea[j>>1]<<16);
      float f=(j&1)?__uint_as_float(fa[j>>1]&0xFFFF0000u):__uint_as_float(fa[j>>1]<<16);
      float w0 = fmaf(e, sreg[j], treg[j]);    // k even
      float w1 = fmaf(f, sreg[j], treg[j]);    // k odd
      union { unsigned short h[2]; unsigned int u; } p;
      p.h[0]=b16(w0); p.h[1]=b16(w1);
      Ws32[(8*bc + j)*17 + kp] = p.u;
    }
    __syncthreads();
    {
      unsigned int v[8];
      #pragma unroll
      for (int cidx=0;cidx<8;cidx++) v[cidx] = Ws32[prow*17 + phalf*8 + cidx];
      uint4 u0 = make_uint4(v[0],v[1],v[2],v[3]);
      uint4 u1 = make_uint4(v[4],v[5],v[6],v[7]);
      unsigned short* dst = Wt + (size_t)(n0 + prow)*KK + k0 + s*32 + phalf*16;
      *(uint4*)(dst)     = u0;
      *(uint4*)(dst + 8) = u1;
    }
    __syncthreads();
  }
}

// ---------------- pass 2: 256x256 / BK=64 / 8-wave phase-split GEMM ----------------
// Round-1-measured schedule (413 us, MfmaUtil 38.7, 0 bank conflicts) plus:
//  (a) sched_barrier(0) pins each ds_read/stage group ABOVE its s_barrier
//      (raw s_barrier is not an LLVM memory fence; reads could legally sink
//      below it, serializing the phase). Correctness-neutral.
//  (b) XCD-bijective chunked grid swizzle (688 = 8*86): XCD k owns m-rows
//      {2k,2k+1} x all 43 n-cols -> its 4MB of A pins in its private L2,
//      B streams via L3 once. Target: FETCH_SIZE 401MB -> ~150-250MB.
__global__ __launch_bounds__(512, 2) void gemm256(
    const unsigned short* __restrict__ A,   // [M,K] bf16
    const unsigned short* __restrict__ B,   // [N,K] bf16
    const float* __restrict__ bias,
    float* __restrict__ out){
  extern __shared__ __align__(16) unsigned short smem[];  // 131072 B dynamic
  const int tid  = threadIdx.x;
  const int lane = tid & 63;
  const int wid  = tid >> 6;
  const int l16  = lane & 15;
  const int quad = lane >> 4;
  const int wm   = wid >> 2;        // 0..1  -> A rows wm*128..+127
  const int wn   = wid & 3;         // 0..3  -> B rows wn*64..+63
  // XCD-bijective swizzle: id&7 = XCD (round-robin dispatch); each XCD gets
  // 86 consecutive sw values = 2 m-rows x 43 n-cols.
  const int id   = blockIdx.x;                 // 0..687
  const int sw   = (id & 7) * 86 + (id >> 3);  // bijective (688 = 8*86)
  const int m0   = (sw / 43) * 256;
  const int n0   = (sw % 43) * 256;

  // ds_read swizzle: chunk xor value is mi/ni-independent (rows step by 16)
  const int xv0  = (quad ^ (l16 & 7)) << 3;   // khalf0 chunk offset (elems)
  const int xv1  = xv0 ^ 32;                  // khalf1 (= ^ (4<<3))
  const int rowA = (wm*128 + l16) * 64;            // elem offset in A region
  const int rowB = 16384 + (wn*64 + l16) * 64;     // elem offset, B region

  // stage addressing: thread t covers linear LDS bytes t*16 (+8KB for call 1);
  // inverse-swizzled global source row/col:
  const int srl   = tid >> 3;                              // 0..63
  const int scol  = ((tid & 7) ^ ((tid >> 3) & 7)) << 3;   // elem col, 8-aligned
  const int sloff = tid * 8;                               // ushort off in 8KB

#define STAGE(mat, hf, s) do { \
    const unsigned short* gsrc = ((mat) ? B + (size_t)(n0 + (hf)*128 + srl)*KK \
                                        : A + (size_t)(m0 + (hf)*128 + srl)*KK) \
                                 + (size_t)(s)*64 + scol; \
    unsigned short* ldst = smem + (((s)&1)<<15) + ((mat)<<14) + ((hf)<<13) + sloff; \
    g2l16(gsrc, ldst); \
    g2l16(gsrc + (size_t)64*KK, ldst + 4096); \
  } while(0)

  f32x4 acc[8][4];
  {
    float bv[4];
    #pragma unroll
    for (int ni=0;ni<4;ni++) bv[ni] = bias[n0 + wn*64 + ni*16 + l16];
    #pragma unroll
    for (int mi=0;mi<8;mi++)
      #pragma unroll
      for (int ni=0;ni<4;ni++)
        acc[mi][ni] = (f32x4){bv[ni], bv[ni], bv[ni], bv[ni]};
  }

  // prologue: K0 fully + K1 fully in flight; wait for K0 only (vmcnt(8))
  STAGE(0,0,0); STAGE(0,1,0); STAGE(1,0,0); STAGE(1,1,0);
  STAGE(0,0,1); STAGE(0,1,1); STAGE(1,0,1); STAGE(1,1,1);
  asm volatile("s_waitcnt vmcnt(8)" ::: "memory");
  __builtin_amdgcn_s_barrier();

  #pragma unroll 1
  for (int t = 0; t < KSTEPS; ++t){
    const unsigned short* Ab = smem + ((t&1)<<15);
    bf16x8 af0[8], af1[8], bf0[4], bf1[4];

    // ---- phase 1: read khalf0 frags; MFMA kh0 x ni{0,1}
    #pragma unroll
    for (int mi=0;mi<8;mi++){ U16 u; u.u = *(const uint4*)(Ab + rowA + mi*1024 + xv0); af0[mi]=u.v; }
    #pragma unroll
    for (int ni=0;ni<4;ni++){ U16 u; u.u = *(const uint4*)(Ab + rowB + ni*1024 + xv0); bf0[ni]=u.v; }
    __builtin_amdgcn_sched_barrier(0);          // pin reads above the barrier
    __builtin_amdgcn_s_barrier();
    __builtin_amdgcn_s_setprio(1);
    #pragma unroll
    for (int mi=0;mi<8;mi++){
      acc[mi][0] = __builtin_amdgcn_mfma_f32_16x16x32_bf16(af0[mi], bf0[0], acc[mi][0], 0,0,0);
      acc[mi][1] = __builtin_amdgcn_mfma_f32_16x16x32_bf16(af0[mi], bf0[1], acc[mi][1], 0,0,0);
    }
    __builtin_amdgcn_s_setprio(0);
    __builtin_amdgcn_s_barrier();

    // ---- phase 2: read khalf1 frags; MFMA kh0 x ni{2,3}
    #pragma unroll
    for (int mi=0;mi<8;mi++){ U16 u; u.u = *(const uint4*)(Ab + rowA + mi*1024 + xv1); af1[mi]=u.v; }
    #pragma unroll
    for (int ni=0;ni<4;ni++){ U16 u; u.u = *(const uint4*)(Ab + rowB + ni*1024 + xv1); bf1[ni]=u.v; }
    __builtin_amdgcn_sched_barrier(0);          // pin reads above the barrier
    __builtin_amdgcn_s_barrier();
    __builtin_amdgcn_s_setprio(1);
    #pragma unroll
    for (int mi=0;mi<8;mi++){
      acc[mi][2] = __builtin_amdgcn_mfma_f32_16x16x32_bf16(af0[mi], bf0[2], acc[mi][2], 0,0,0);
      acc[mi][3] = __builtin_amdgcn_mfma_f32_16x16x32_bf16(af0[mi], bf0[3], acc[mi][3], 0,0,0);
    }
    __builtin_amdgcn_s_setprio(0);
    __builtin_amdgcn_s_barrier();
    // all reads of buf(t&1) are now complete in every wave -> safe to restage it

    // ---- phase 3: stage K+2 (A-lo, B-lo) into buf(t&1); MFMA kh1 x ni{0,1}
    if (t + 2 < KSTEPS){ STAGE(0,0,t+2); STAGE(1,0,t+2); }
    __builtin_amdgcn_sched_barrier(0);          // pin stages above the barrier
    __builtin_amdgcn_s_barrier();
    __builtin_amdgcn_s_setprio(1);
    #pragma unroll
    for (int mi=0;mi<8;mi++){
      acc[mi][0] = __builtin_amdgcn_mfma_f32_16x16x32_bf16(af1[mi], bf1[0], acc[mi][0], 0,0,0);
      acc[mi][1] = __builtin_amdgcn_mfma_f32_16x16x32_bf16(af1[mi], bf1[1], acc[mi][1], 0,0,0);
    }
    __builtin_amdgcn_s_setprio(0);
    __builtin_amdgcn_s_barrier();

    // ---- phase 4: stage K+2 (A-hi, B-hi); MFMA kh1 x ni{2,3}; counted wait
    if (t + 2 < KSTEPS){ STAGE(0,1,t+2); STAGE(1,1,t+2); }
    __builtin_amdgcn_sched_barrier(0);          // pin stages above the barrier
    __builtin_amdgcn_s_barrier();
    __builtin_amdgcn_s_setprio(1);
    #pragma unroll
    for (int mi=0;mi<8;mi++){
      acc[mi][2] = __builtin_amdgcn_mfma_f32_16x16x32_bf16(af1[mi], bf1[2], acc[mi][2], 0,0,0);
      acc[mi][3] = __builtin_amdgcn_mfma_f32_16x16x32_bf16(af1[mi], bf1[3], acc[mi][3], 0,0,0);
    }
    __builtin_amdgcn_s_setprio(0);
    // K+1 must be landed before next iteration's reads; K+2's 8 loads may fly.
    if (t < KSTEPS - 2) asm volatile("s_waitcnt vmcnt(8)" ::: "memory");
    else                asm volatile("s_waitcnt vmcnt(0)" ::: "memory");
    __builtin_amdgcn_s_barrier();
  }
#undef STAGE

  #pragma unroll
  for (int mi=0;mi<8;mi++)
    #pragma unroll
    for (int ni=0;ni<4;ni++){
      const int n = n0 + wn*64 + ni*16 + l16;
      #pragma unroll
      for (int r=0;r<4;r++){
        const int m = m0 + wm*128 + mi*16 + quad*4 + r;
        out[(size_t)m*NN + n] = acc[mi][ni][r];
      }
    }
}

// ---------------- fallback: round-4 fused kernel (passing, 705 us) ----------------
__global__ __launch_bounds__(256, 3) void awq_gemm_fused(
    const float* __restrict__ x, const int* __restrict__ qweight,
    const int* __restrict__ qzeros, const float* __restrict__ scales,
    const float* __restrict__ bias, float* __restrict__ out){
  __shared__ __align__(16) unsigned short As[128*LDA];
  __shared__ __align__(16) unsigned short Bs[128*LDB];
  const int tid  = threadIdx.x;
  const int wid  = tid >> 6;
  const int lane = tid & 63;
  const int l16  = lane & 15;
  const int quad = lane >> 4;
  const int wm   = (wid >> 1) * 64;
  const int wn   = (wid & 1) * 64;
  const int m0   = blockIdx.y * 128;
  const int n0   = blockIdx.x * 128;
  const int c0   = blockIdx.x * 16;
  const int ar = tid >> 3, kq = tid & 7;
  const float* pax = x + (size_t)(m0 + ar)*KK + kq*4;
  const int bc  = tid & 15;
  const int br0 = (tid >> 4) * 2;
  const int* pb = qweight + (size_t)br0*NP8 + c0 + bc;
  const int SH[8] = {0,16,4,20,8,24,12,28};
  float sreg[8], treg[8];
  f32x4 acc[4][4];
  {
    float bv[4];
    #pragma unroll
    for (int ni=0;ni<4;ni++) bv[ni] = bias[n0 + wn + ni*16 + l16];
    #pragma unroll
    for (int mi=0;mi<4;mi++)
      #pragma unroll
      for (int ni=0;ni<4;ni++)
        acc[mi][ni] = (f32x4){bv[ni], bv[ni], bv[ni], bv[ni]};
  }
  #pragma unroll 1
  for (int kt = 0; kt < KTILES; ++kt) {
    f32x4 av[4];
    #pragma unroll
    for (int i=0;i<4;i++) av[i] = *(const f32x4*)(pax + (size_t)i*32*KK);
    unsigned int q0 = (unsigned int)pb[0];
    unsigned int q1 = (unsigned int)pb[NP8];
    pax += 32; pb += (size_t)32*NP8;
    if ((kt & 3) == 0) {
      const int g = kt >> 2;
      const float* sp = scales + (size_t)g*NN + n0 + 8*bc;
      unsigned int qz = (unsigned int)qzeros[(size_t)g*NP8 + c0 + bc];
      #pragma unroll
      for (int j=0;j<8;j++){
        float s = sp[j];
        float z = (float)((qz >> SH[j]) & 0xFu);
        sreg[j] = s; treg[j] = -(128.0f + z) * s;
      }
    }
    __syncthreads();
    #pragma unroll
    for (int i=0;i<4;i++){
      union { unsigned short s[4]; uint2 u; } t;
      t.s[0]=b16(av[i][0]); t.s[1]=b16(av[i][1]);
      t.s[2]=b16(av[i][2]); t.s[3]=b16(av[i][3]);
      *(uint2*)(&As[(i*32 + ar)*LDA + kq*4]) = t.u;
    }
    {
      const unsigned int M4v = 0x000F000Fu, BBv = 0x43004300u;
      unsigned int ea[4], fa[4];
      ea[0]=(q0&M4v)|BBv; ea[1]=((q0>>4)&M4v)|BBv; ea[2]=((q0>>8)&M4v)|BBv; ea[3]=((q0>>12)&M4v)|BBv;
      fa[0]=(q1&M4v)|BBv; fa[1]=((q1>>4)&M4v)|BBv; fa[2]=((q1>>8)&M4v)|BBv; fa[3]=((q1>>12)&M4v)|BBv;
      #pragma unroll
      for (int j=0;j<8;j++){
        float e=(j&1)?__uint_as_float(ea[j>>1]&0xFFFF0000u):__uint_as_float(ea[j>>1]<<16);
        float f=(j&1)?__uint_as_float(fa[j>>1]&0xFFFF0000u):__uint_as_float(fa[j>>1]<<16);
        union { unsigned short s[2]; unsigned int u; } t;
        t.s[0]=b16(fmaf(e,sreg[j],treg[j])); t.s[1]=b16(fmaf(f,sreg[j],treg[j]));
        *(unsigned int*)(&Bs[(8*bc + j)*LDB + br0]) = t.u;
      }
    }
    __syncthreads();
    bf16x8 af[4], bfr[4];
    #pragma unroll
    for (int mi=0;mi<4;mi++){
      union { uint4 u; bf16x8 v; } t;
      t.u = *(const uint4*)(&As[(wm + mi*16 + l16)*LDA + quad*8]);
      af[mi] = t.v;
    }
    #pragma unroll
    for (int ni=0;ni<4;ni++){
      const unsigned int* bp = (const unsigned int*)(&Bs[(wn + ni*16 + l16)*LDB + quad*8]);
      union { unsigned int u[4]; bf16x8 v; } t;
      t.u[0]=bp[0]; t.u[1]=bp[1]; t.u[2]=bp[2]; t.u[3]=bp[3];
      bfr[ni] = t.v;
    }
    #pragma unroll
    for (int mi=0;mi<4;mi++)
      #pragma unroll
      for (int ni=0;ni<4;ni++)
        acc[mi][ni] = __builtin_amdgcn_mfma_f32_16x16x32_bf16(af[mi], bfr[ni], acc[mi][ni], 0, 0, 0);
  }
  #pragma unroll
  for (int mi=0;mi<4;mi++)
    #pragma unroll
    for (int ni=0;ni<4;ni++){
      const int n = n0 + wn + ni*16 + l16;
      #pragma unroll
      for (int r=0;r<4;r++){
        const int m = m0 + wm + mi*16 + quad*4 + r;
        out[(size_t)m*NN + n] = acc[mi][ni][r];
      }
    }
}

extern "C" void kernel_launch(void* const* d_in, const int* in_sizes, int n_in,
                              void* d_out, int out_size, void* d_ws, size_t ws_size,
                              hipStream_t stream) {
  const float* x  = (const float*)d_in[0];
  const int* qw   = (const int*)d_in[1];
  const int* qz   = (const int*)d_in[2];
  const float* sc = (const float*)d_in[3];
  const float* bi = (const float*)d_in[4];
  float* out = (float*)d_out;

  if (ws_size >= WS_NEED) {
    static int s_attr_done = 0;
    if (!s_attr_done) {
      hipFuncSetAttribute(reinterpret_cast<const void*>(gemm256),
                          hipFuncAttributeMaxDynamicSharedMemorySize, 131072);
      s_attr_done = 1;
    }
    unsigned short* Wt = (unsigned short*)d_ws;                    // [N,K] bf16
    unsigned short* xb = (unsigned short*)((char*)d_ws + W_BYTES); // [M,K] bf16
    prep_fused<<<NDQ + NCV, 256, 0, stream>>>(x, qw, qz, sc, Wt, xb);
    gemm256<<<dim3(688), 512, 131072, stream>>>(xb, Wt, bi, out);
  } else {
    awq_gemm_fused<<<dim3(NN/128, MM/128), 256, 0, stream>>>(x, qw, qz, sc, bi, out);
  }
}